// Round 4
// baseline (219.702 us; speedup 1.0000x reference)
//
#include <hip/hip_runtime.h>
#include <hip/hip_bf16.h>
#include <stdint.h>

// B=32, C=128->128, 56x56, 3x3 pad 1, two quantized branches fused as one
// conv with IC2=256.  R4: exact-int8 implicit GEMM (mfma_i32_16x16x64_i8),
// XOR-swizzled LDS, dual i32 accumulators + fp32 epilogue scaling.
#define BATCH 32
#define CH 128
#define HH 56
#define WW 56
#define HW 3136
#define M_TOTAL (BATCH*HW)

using int4v    = __attribute__((ext_vector_type(4))) int;
using float4v  = __attribute__((ext_vector_type(4))) float;

// ws layout (bytes):
//   wqb : i8   [9][128 oc][256 ic2] = 294,912   (B^T: ic contiguous)
//   scb : f32  sc_h[128], sc_l[128], bias[128] = 1,536
//   zp  : 256 B pattern page (bytes 0..127 = 0x80, 128..255 = 0x00)
//   aqn : i8   [32][56][56][256]    = 25,690,112 (NHWC; high: k-128, low: k)
//   msk : u8   [32][128][7][7]      = 200,704
#define WQB_OFF 0
#define SCB_OFF 294912
#define ZP_OFF  296448
#define AQN_OFF 296704
#define MSK_OFF (296704 + 25690112)

#define GLD_LDS16(g, l)                                                        \
  __builtin_amdgcn_global_load_lds(                                            \
      (const __attribute__((address_space(1))) void*)(g),                      \
      (__attribute__((address_space(3))) void*)(l), 16, 0, 0)

// ---------------- Kernel 1: per-OC weight quant -> int8 B^T + scales --------
__global__ __launch_bounds__(256) void quant_w_kernel(
    const float* __restrict__ wh, const float* __restrict__ wl,
    const float* __restrict__ p_sh, const float* __restrict__ p_sl,
    char* __restrict__ wqb, float* __restrict__ scb, int* __restrict__ zp) {
  int blk = blockIdx.x;
  int which = blk >> 7, oc = blk & 127;
  if (blk == 0 && threadIdx.x < 64)
    zp[threadIdx.x] = (threadIdx.x < 32) ? 0x80808080 : 0;  // pad pattern
  const float* src = (which ? wl : wh) + (size_t)oc * 1152;
  float n = which ? 7.0f : 127.0f;  // signed narrow-range 2^(b-1)-1

  __shared__ float red[256];
  __shared__ int ired[256];
  float m = 0.0f;
  for (int e = threadIdx.x; e < 1152; e += 256) m = fmaxf(m, fabsf(src[e]));
  red[threadIdx.x] = m;
  __syncthreads();
  for (int s = 128; s > 0; s >>= 1) {
    if (threadIdx.x < s) red[threadIdx.x] = fmaxf(red[threadIdx.x], red[threadIdx.x + s]);
    __syncthreads();
  }
  float scale = red[0] / n;

  int partial = 0;
  for (int e = threadIdx.x; e < 1152; e += 256) {
    int tt = e >> 7, ic = e & 127;
    float q = rintf(src[ic * 9 + tt] / scale);  // jnp.round = RNE = rintf
    q = fminf(fmaxf(q, -n), n);
    int k = (int)q;
    partial += k;
    wqb[((size_t)tt * 128 + oc) * 256 + which * 128 + ic] = (char)k;
  }
  ired[threadIdx.x] = partial;
  __syncthreads();
  for (int s = 128; s > 0; s >>= 1) {
    if (threadIdx.x < s) ired[threadIdx.x] += ired[threadIdx.x + s];
    __syncthreads();
  }
  if (threadIdx.x == 0) {
    float s_act = which ? p_sl[0] : p_sh[0];
    float sc = s_act * scale;
    if (which == 0) {
      scb[oc] = sc;                                   // sc_h
      scb[256 + oc] = sc * 128.0f * (float)ired[0];   // bias (offset correction)
    } else {
      scb[128 + oc] = sc;                             // sc_l
    }
  }
}

// ---------------- Kernel 2a: predictor mask ---------------------------------
__global__ __launch_bounds__(256) void mask_kernel(
    const float* __restrict__ x, unsigned char* __restrict__ msk) {
  int bc = blockIdx.x;  // b*128 + c
  __shared__ float4v sx4[784];
  __shared__ float pp[196];
  const float4v* xp4 = (const float4v*)(x + (size_t)bc * HW);
  int t = threadIdx.x;
  #pragma unroll
  for (int i = 0; i < 4; ++i) {
    int idx = t + i * 256;
    if (idx < 784) sx4[idx] = xp4[idx];
  }
  __syncthreads();
  const float* sx = (const float*)sx4;
  if (t < 196) {
    int cell = t >> 2, sub = t & 3;
    int bh = cell / 7, bw = cell % 7;
    int r0 = bh * 8 + sub * 2;
    float s = 0.0f;
    #pragma unroll
    for (int rr = 0; rr < 2; ++rr)
      #pragma unroll
      for (int j = 0; j < 8; ++j)
        s += sx[(r0 + rr) * WW + bw * 8 + j];
    pp[t] = s;
  }
  __syncthreads();
  if (t < 49) {
    float s = pp[t * 4] + pp[t * 4 + 1] + pp[t * 4 + 2] + pp[t * 4 + 3];
    msk[(size_t)bc * 49 + t] = (s * (1.0f / 64.0f) >= 0.05f) ? 1 : 0;
  }
}

// ---------------- Kernel 2b: act quant -> int8 NHWC -------------------------
// grid = (b*56 + h).  Bank-rotated LDS transpose, 16 B/lane stores.
#define SXS 88
#define ROT(c) ((((c) >> 4) & 7) * 4)
__global__ __launch_bounds__(256) void quant_a_kernel(
    const float* __restrict__ x, const unsigned char* __restrict__ msk,
    const float* __restrict__ p_sh, const float* __restrict__ p_sl,
    char* __restrict__ aqn) {
  int bh = blockIdx.x;
  int b = bh / HH, h = bh - b * HH;
  __shared__ float sx[128 * SXS];
  __shared__ unsigned char sm[128 * 8];
  int t = threadIdx.x;
  #pragma unroll
  for (int i = 0; i < 7; ++i) {  // 1792 float4 = 128 c x 14
    int idx = t + i * 256;
    int c = idx / 14, w4 = idx - c * 14;
    *(float4v*)(sx + c * SXS + ROT(c) + w4 * 4) =
        *(const float4v*)(x + ((size_t)(b * 128 + c)) * HW + h * 56 + w4 * 4);
  }
  for (int idx = t; idx < 128 * 7; idx += 256) {
    int c = idx / 7, bw = idx - c * 7;
    sm[c * 8 + bw] = msk[((size_t)(b * 128 + c)) * 49 + (h >> 3) * 7 + bw];
  }
  __syncthreads();
  float shs = p_sh[0], sls = p_sl[0];
  int cb = (t & 15) * 16;          // 16 consecutive c2 per thread
  #pragma unroll
  for (int p = 0; p < 4; ++p) {
    int pw = p * 16 + (t >> 4);
    if (pw < WW) {
      int mcell = pw >> 3;
      int wq[4] = {0, 0, 0, 0};
      #pragma unroll
      for (int k = 0; k < 16; ++k) {
        int c2 = cb + k;
        int c = c2 & 127;
        float xv = sx[c * SXS + ROT(c) + pw];
        bool mk = sm[c * 8 + mcell] != 0;
        int kk;
        if (c2 < 128) {  // high branch: uint8, store k-128
          float xh = mk ? xv : 1e-5f;
          kk = (int)fminf(fmaxf(rintf(xh / shs), 0.0f), 255.0f) - 128;
        } else {         // low branch: 4-bit uint, fits signed i8
          float xl = mk ? 1e-5f : xv;
          kk = (int)fminf(fmaxf(rintf(xl / sls), 0.0f), 15.0f);
        }
        wq[k >> 2] |= (kk & 0xff) << ((k & 3) * 8);
      }
      *(int4v*)(aqn + ((size_t)bh * 56 + pw) * 256 + cb) =
          (int4v){wq[0], wq[1], wq[2], wq[3]};
    }
  }
}

// ---------------- Kernel 3: implicit-GEMM i8 MFMA conv ----------------------
// Block 128m x 128oc.  K = 3 dh x (2 high + 2 low chunks of 64 ic).
// Per chunk: stage A (160 rows x 64 B, XOR-swizzled) + B (384 rows x 64 B),
// then 3 dw x 16 mfma_i32_16x16x64_i8 per wave.  12 barrier pairs.
__global__ __launch_bounds__(256) void conv_mfma_kernel(
    const char* __restrict__ wqb,
    const char* __restrict__ aqn,
    const char* __restrict__ zp,
    const float* __restrict__ scb,
    float* __restrict__ out) {
  __shared__ __align__(16) char As[160 * 64];  // 10 KB
  __shared__ __align__(16) char Bs[384 * 64];  // 24 KB

  int tid = threadIdx.x;
  int lane = tid & 63, wv = tid >> 6;
  int wm = wv & 1, wn = wv >> 1;
  int lr = lane & 15, quad = lane >> 4;
  int m0 = blockIdx.x * 128;

  // ---- A staging precompute: 10 groups of 16 rows; wave -> {wv, wv+4, wv+8}
  int ng = (wv < 2) ? 3 : 2;
  int sgrp[3] = {wv, wv + 4, wv + 8};
  const char* abase[3];
  const char* zbase[3];
  int avalid[3], ah[3];
  #pragma unroll
  for (int j = 0; j < 3; ++j) {
    int slot = sgrp[j] * 16 + (lane >> 2);
    int qp = (((lane & 3) ^ (slot >> 1)) & 3) * 16;  // XOR swizzle quarter
    int p = m0 + slot - 16;
    int pv = (p >= 0) && (p < M_TOTAL);
    int pc = pv ? p : 0;
    int bb = pc / HW, rem = pc - bb * HW;
    int hh = rem / 56, ww2 = rem - hh * 56;
    abase[j] = aqn + ((size_t)(bb * HW + hh * 56 + ww2)) * 256 + qp;
    zbase[j] = zp + qp;
    avalid[j] = pv;
    ah[j] = hh;
  }
  // ---- B staging precompute: 6 groups per wave
  const char* bbase[6];
  #pragma unroll
  for (int i = 0; i < 6; ++i) {
    int slot = wv * 96 + i * 16 + (lane >> 2);
    int qp = (((lane & 3) ^ (slot >> 1)) & 3) * 16;
    bbase[i] = wqb + (size_t)slot * 256 + qp;
  }
  // ---- w-edge masks per m-fragment
  int lo_ok[4], hi_ok[4];
  #pragma unroll
  for (int mi = 0; mi < 4; ++mi) {
    int m = m0 + wm * 64 + mi * 16 + lr;
    int w = (m % HW) % 56;
    lo_ok[mi] = (w > 0);
    hi_ok[mi] = (w < 55);
  }

  int4v acch[4][4], accl[4][4];
  #pragma unroll
  for (int mi = 0; mi < 4; ++mi)
    #pragma unroll
    for (int ni = 0; ni < 4; ++ni) {
      acch[mi][ni] = (int4v){0, 0, 0, 0};
      accl[mi][ni] = (int4v){0, 0, 0, 0};
    }

  for (int dh3 = 0; dh3 < 3; ++dh3) {
    int dh = dh3 - 1;
    const char* asrc[3];
    #pragma unroll
    for (int j = 0; j < 3; ++j) {
      int h2 = ah[j] + dh;
      bool ok = avalid[j] && ((unsigned)h2 < (unsigned)HH);
      asrc[j] = ok ? (abase[j] + dh * (56 * 256)) : zbase[j];
    }
    const size_t boff = (size_t)dh3 * 98304;  // 3-tap slab
    #pragma unroll
    for (int icc = 0; icc < 4; ++icc) {
      int ic0 = icc * 64;
      const bool high = (icc < 2);
      const int patv = high ? (int)0x80808080 : 0;  // pad byte per branch
      const int4v pat = (int4v){patv, patv, patv, patv};
      __syncthreads();
      #pragma unroll
      for (int j = 0; j < 3; ++j)
        if (j < ng) GLD_LDS16(asrc[j] + ic0, As + sgrp[j] * 1024);
      #pragma unroll
      for (int i = 0; i < 6; ++i)
        GLD_LDS16(bbase[i] + boff + ic0, Bs + (wv * 96 + i * 16) * 64);
      __syncthreads();

      #pragma unroll
      for (int dwi = 0; dwi < 3; ++dwi) {
        int4v af[4], bf[4];
        #pragma unroll
        for (int mi = 0; mi < 4; ++mi) {
          int sA = wm * 64 + mi * 16 + lr + 15 + dwi;
          af[mi] = *(const int4v*)(As + sA * 64 + (((quad ^ (sA >> 1)) & 3) * 16));
          bool ok = (dwi == 1) | (dwi == 0 ? lo_ok[mi] : hi_ok[mi]);
          af[mi] = ok ? af[mi] : pat;
        }
        #pragma unroll
        for (int ni = 0; ni < 4; ++ni) {
          int sB = dwi * 128 + wn * 64 + ni * 16 + lr;
          bf[ni] = *(const int4v*)(Bs + sB * 64 + (((quad ^ (sB >> 1)) & 3) * 16));
        }
        if (high) {
          #pragma unroll
          for (int mi = 0; mi < 4; ++mi)
            #pragma unroll
            for (int ni = 0; ni < 4; ++ni)
              acch[mi][ni] = __builtin_amdgcn_mfma_i32_16x16x64_i8(
                  af[mi], bf[ni], acch[mi][ni], 0, 0, 0);
        } else {
          #pragma unroll
          for (int mi = 0; mi < 4; ++mi)
            #pragma unroll
            for (int ni = 0; ni < 4; ++ni)
              accl[mi][ni] = __builtin_amdgcn_mfma_i32_16x16x64_i8(
                  af[mi], bf[ni], accl[mi][ni], 0, 0, 0);
        }
      }
    }
  }

  // ---- Epilogue: y = sc_h*acc_h + sc_l*acc_l + bias, direct dwordx4 stores
  #pragma unroll
  for (int mi = 0; mi < 4; ++mi) {
    int m = m0 + wm * 64 + mi * 16 + quad * 4;
    int b = m / HW, r = m - b * HW;
    float* obase = out + (size_t)b * (CH * HW) + r;
    #pragma unroll
    for (int ni = 0; ni < 4; ++ni) {
      int oc = wn * 64 + ni * 16 + lr;
      float sch = scb[oc], scl = scb[128 + oc], bs = scb[256 + oc];
      float4v f;
      #pragma unroll
      for (int rg = 0; rg < 4; ++rg)
        f[rg] = sch * (float)acch[mi][ni][rg] + scl * (float)accl[mi][ni][rg] + bs;
      *(float4v*)(obase + (size_t)oc * HW) = f;
    }
  }
}

extern "C" void kernel_launch(void* const* d_in, const int* in_sizes, int n_in,
                              void* d_out, int out_size, void* d_ws, size_t ws_size,
                              hipStream_t stream) {
  const float* x  = (const float*)d_in[0];
  const float* wh = (const float*)d_in[1];
  const float* wl = (const float*)d_in[2];
  const float* sh = (const float*)d_in[3];
  const float* sl = (const float*)d_in[4];
  float* out = (float*)d_out;

  char* ws = (char*)d_ws;
  char* wqb  = ws + WQB_OFF;
  float* scb = (float*)(ws + SCB_OFF);
  int* zp    = (int*)(ws + ZP_OFF);
  char* aqn  = ws + AQN_OFF;
  unsigned char* msk = (unsigned char*)(ws + MSK_OFF);

  quant_w_kernel<<<dim3(256), dim3(256), 0, stream>>>(wh, wl, sh, sl, wqb, scb, zp);
  mask_kernel<<<dim3(BATCH * CH), dim3(256), 0, stream>>>(x, msk);
  quant_a_kernel<<<dim3(BATCH * HH), dim3(256), 0, stream>>>(x, msk, sh, sl, aqn);
  conv_mfma_kernel<<<dim3(M_TOTAL / 128), dim3(256), 0, stream>>>(
      wqb, aqn, (const char*)zp, scb, out);
}

// Round 5
// 193.637 us; speedup vs baseline: 1.1346x; 1.1346x over previous
//
#include <hip/hip_runtime.h>
#include <hip/hip_bf16.h>
#include <stdint.h>

// B=32, C=128->128, 56x56, 3x3 pad 1, two quantized branches fused as one
// conv with IC2=256.  R5: exact-int8 implicit GEMM, wave tile 64x32 so the
// dual (high/low) i32 accumulators cost 64 AGPR not 128 -> 4 blocks/CU.
// Fused mask+act-quant prep kernel.
#define BATCH 32
#define CH 128
#define HH 56
#define WW 56
#define HW 3136
#define M_TOTAL (BATCH*HW)

using int4v   = __attribute__((ext_vector_type(4))) int;
using float4v = __attribute__((ext_vector_type(4))) float;

// ws layout (bytes):
//   wqb : i8  [9][128 oc][256 ic2] = 294,912  (B^T: ic contiguous)
//   scb : f32 sc_h[128], sc_l[128], bias[128] = 1,536
//   zp  : 256 B pattern page (bytes 0..127 = 0x80, 128..255 = 0x00)
//   aqn : i8  [32][56][56][256]    = 25,690,112 (NHWC; high: k-128, low: k)
#define WQB_OFF 0
#define SCB_OFF 294912
#define ZP_OFF  296448
#define AQN_OFF 296704

#define GLD_LDS16(g, l)                                                        \
  __builtin_amdgcn_global_load_lds(                                            \
      (const __attribute__((address_space(1))) void*)(g),                      \
      (__attribute__((address_space(3))) void*)(l), 16, 0, 0)

// ---------------- Kernel 1: per-OC weight quant -> int8 B^T + scales --------
__global__ __launch_bounds__(256) void quant_w_kernel(
    const float* __restrict__ wh, const float* __restrict__ wl,
    const float* __restrict__ p_sh, const float* __restrict__ p_sl,
    char* __restrict__ wqb, float* __restrict__ scb, int* __restrict__ zp) {
  int blk = blockIdx.x;
  int which = blk >> 7, oc = blk & 127;
  if (blk == 0 && threadIdx.x < 64)
    zp[threadIdx.x] = (threadIdx.x < 32) ? 0x80808080 : 0;  // pad pattern
  const float* src = (which ? wl : wh) + (size_t)oc * 1152;
  float n = which ? 7.0f : 127.0f;  // signed narrow-range 2^(b-1)-1

  __shared__ float red[256];
  __shared__ int ired[256];
  float m = 0.0f;
  for (int e = threadIdx.x; e < 1152; e += 256) m = fmaxf(m, fabsf(src[e]));
  red[threadIdx.x] = m;
  __syncthreads();
  for (int s = 128; s > 0; s >>= 1) {
    if (threadIdx.x < s) red[threadIdx.x] = fmaxf(red[threadIdx.x], red[threadIdx.x + s]);
    __syncthreads();
  }
  float scale = red[0] / n;

  int partial = 0;
  for (int e = threadIdx.x; e < 1152; e += 256) {
    int tt = e >> 7, ic = e & 127;
    float q = rintf(src[ic * 9 + tt] / scale);  // jnp.round = RNE = rintf
    q = fminf(fmaxf(q, -n), n);
    int k = (int)q;
    partial += k;
    wqb[((size_t)tt * 128 + oc) * 256 + which * 128 + ic] = (char)k;
  }
  ired[threadIdx.x] = partial;
  __syncthreads();
  for (int s = 128; s > 0; s >>= 1) {
    if (threadIdx.x < s) ired[threadIdx.x] += ired[threadIdx.x + s];
    __syncthreads();
  }
  if (threadIdx.x == 0) {
    float s_act = which ? p_sl[0] : p_sh[0];
    float sc = s_act * scale;
    if (which == 0) {
      scb[oc] = sc;                                   // sc_h
      scb[256 + oc] = sc * 128.0f * (float)ired[0];   // offset-correction bias
    } else {
      scb[128 + oc] = sc;                             // sc_l
    }
  }
}

// ---------------- Kernel 2: fused predictor mask + act quant ----------------
// Block per (b, 8-row band, 16-channel group): 32*7*8 = 1792 blocks.
// Reads x once, pools 8x8 cells, quantizes both branches, writes int8 NHWC.
#define KSTR 484   // per-channel LDS stride (floats): 8*60 + 4 pad (bank decorrelate)
__global__ __launch_bounds__(256) void maskquant_kernel(
    const float* __restrict__ x, const float* __restrict__ p_sh,
    const float* __restrict__ p_sl, char* __restrict__ aqn) {
  int bi = blockIdx.x;            // (b*7 + band)*8 + cg
  int cg = bi & 7;
  int bb = bi >> 3;
  int b = bb / 7, band = bb - b * 7;
  __shared__ float sx[16 * KSTR];       // [k][r][60]
  __shared__ float smk[16 * 7];
  int t = threadIdx.x;
  #pragma unroll
  for (int i = 0; i < 7; ++i) {         // 1792 float4 = 16 k x 8 r x 14
    int idx = i * 256 + t;
    int k = idx / 112, rem = idx - k * 112;
    int r = rem / 14, w4 = rem - r * 14;
    *(float4v*)(sx + k * KSTR + r * 60 + w4 * 4) =
        *(const float4v*)(x + ((size_t)(b * 128 + cg * 16 + k)) * HW
                            + (band * 8 + r) * 56 + w4 * 4);
  }
  __syncthreads();
  if (t < 112) {                        // 16 k x 7 cells
    int k = t / 7, bw = t - (t / 7) * 7;
    float s = 0.0f;
    #pragma unroll
    for (int r = 0; r < 8; ++r)
      #pragma unroll
      for (int j = 0; j < 8; ++j)
        s += sx[k * KSTR + r * 60 + bw * 8 + j];
    smk[t] = (s * (1.0f / 64.0f) >= 0.05f) ? 1.0f : 0.0f;
  }
  __syncthreads();
  float shs = p_sh[0], sls = p_sl[0];
  #pragma unroll
  for (int it = 0; it < 2; ++it) {
    int pos = it * 256 + t;             // 448 = 8 r x 56 w
    if (pos < 448) {
      int r = pos / 56, w = pos - r * 56;
      int h = band * 8 + r;
      char* base = aqn + (((size_t)(b * 56 + h) * 56 + w) * 256) + cg * 16;
      int hw_[4] = {0, 0, 0, 0}, lw_[4] = {0, 0, 0, 0};
      int mcell = w >> 3;
      #pragma unroll
      for (int k = 0; k < 16; ++k) {
        float xv = sx[k * KSTR + r * 60 + w];
        bool mk = smk[k * 7 + mcell] != 0.0f;
        float xh = mk ? xv : 1e-5f;
        int kh = (int)fminf(fmaxf(rintf(xh / shs), 0.0f), 255.0f) - 128;
        float xl = mk ? 1e-5f : xv;
        int kl = (int)fminf(fmaxf(rintf(xl / sls), 0.0f), 15.0f);
        hw_[k >> 2] |= (kh & 0xff) << ((k & 3) * 8);
        lw_[k >> 2] |= (kl & 0xff) << ((k & 3) * 8);
      }
      *(int4v*)(base)       = (int4v){hw_[0], hw_[1], hw_[2], hw_[3]};  // high
      *(int4v*)(base + 128) = (int4v){lw_[0], lw_[1], lw_[2], lw_[3]};  // low
    }
  }
}

// ---------------- Kernel 3: implicit-GEMM i8 MFMA conv ----------------------
// Grid (784 m-tiles, 2 oc-halves).  Block 128m x 64oc, 4 waves of 64m x 32oc.
// Dual acc = 4mi x 2ni x 2branch int4v = 64 AGPR; launch_bounds forces
// <=128 arch regs -> 4 blocks/CU co-resident (LDS 22 KB).
__global__ __launch_bounds__(256, 4) void conv_mfma_kernel(
    const char* __restrict__ wqb,
    const char* __restrict__ aqn,
    const char* __restrict__ zp,
    const float* __restrict__ scb,
    float* __restrict__ out) {
  __shared__ __align__(16) char As[160 * 64];  // 10 KB (16-row m-halo)
  __shared__ __align__(16) char Bs[192 * 64];  // 12 KB (3 dw taps x 64 oc)

  int tid = threadIdx.x;
  int lane = tid & 63, wv = tid >> 6;
  int wm = wv >> 1, wn = wv & 1;
  int lr = lane & 15, quad = lane >> 4;
  int m0 = blockIdx.x * 128;
  int oc0 = blockIdx.y * 64;

  // ---- A staging precompute: 10 groups of 16 rows; wave -> {wv, wv+4, wv+8}
  int ng = (wv < 2) ? 3 : 2;
  int sgrp[3] = {wv, wv + 4, wv + 8};
  const char* abase[3];
  const char* zbase[3];
  int avalid[3], ah[3];
  #pragma unroll
  for (int j = 0; j < 3; ++j) {
    int slot = sgrp[j] * 16 + (lane >> 2);
    int qp = (((lane & 3) ^ (slot >> 1)) & 3) * 16;  // XOR swizzle quarter
    int p = m0 + slot - 16;
    int pv = (p >= 0) && (p < M_TOTAL);
    int pc = pv ? p : 0;
    int bb = pc / HW, rem = pc - bb * HW;
    int hh = rem / 56, ww2 = rem - hh * 56;
    abase[j] = aqn + ((size_t)(bb * HW + hh * 56 + ww2)) * 256 + qp;
    zbase[j] = zp + qp;
    avalid[j] = pv;
    ah[j] = hh;
  }
  // ---- B staging precompute: 3 groups of 16 rows per wave (192 total)
  const char* bbase[3];
  #pragma unroll
  for (int i = 0; i < 3; ++i) {
    int slot = wv * 48 + i * 16 + (lane >> 2);       // [dwi 3][ocr 64]
    int qp = (((lane & 3) ^ (slot >> 1)) & 3) * 16;
    int dwi_s = slot >> 6, ocr = slot & 63;
    bbase[i] = wqb + ((size_t)(dwi_s * 128 + oc0 + ocr)) * 256 + qp;
  }
  // ---- w-edge masks per m-fragment
  int lo_ok[4], hi_ok[4];
  #pragma unroll
  for (int mi = 0; mi < 4; ++mi) {
    int m = m0 + wm * 64 + mi * 16 + lr;
    int w = (m % HW) % 56;
    lo_ok[mi] = (w > 0);
    hi_ok[mi] = (w < 55);
  }

  int4v acch[4][2], accl[4][2];
  #pragma unroll
  for (int mi = 0; mi < 4; ++mi)
    #pragma unroll
    for (int ni = 0; ni < 2; ++ni) {
      acch[mi][ni] = (int4v){0, 0, 0, 0};
      accl[mi][ni] = (int4v){0, 0, 0, 0};
    }

  for (int dh3 = 0; dh3 < 3; ++dh3) {
    int dh = dh3 - 1;
    const char* asrc[3];
    #pragma unroll
    for (int j = 0; j < 3; ++j) {
      int h2 = ah[j] + dh;
      bool ok = avalid[j] && ((unsigned)h2 < (unsigned)HH);
      asrc[j] = ok ? (abase[j] + dh * (56 * 256)) : zbase[j];
    }
    const size_t boff = (size_t)dh3 * 98304;  // 3-tap slab of wqb
    #pragma unroll
    for (int icc = 0; icc < 4; ++icc) {
      int ic0 = icc * 64;
      const bool high = (icc < 2);
      const int patv = high ? (int)0x80808080 : 0;  // pad byte per branch
      const int4v pat = (int4v){patv, patv, patv, patv};
      __syncthreads();
      #pragma unroll
      for (int j = 0; j < 3; ++j)
        if (j < ng) GLD_LDS16(asrc[j] + ic0, As + sgrp[j] * 1024);
      #pragma unroll
      for (int i = 0; i < 3; ++i)
        GLD_LDS16(bbase[i] + boff + ic0, Bs + (wv * 48 + i * 16) * 64);
      __syncthreads();

      #pragma unroll
      for (int dwi = 0; dwi < 3; ++dwi) {
        int4v af[4], bf[2];
        #pragma unroll
        for (int mi = 0; mi < 4; ++mi) {
          int sA = wm * 64 + mi * 16 + lr + 15 + dwi;
          af[mi] = *(const int4v*)(As + sA * 64 + (((quad ^ (sA >> 1)) & 3) * 16));
          bool ok = (dwi == 1) | (dwi == 0 ? lo_ok[mi] : hi_ok[mi]);
          af[mi] = ok ? af[mi] : pat;
        }
        #pragma unroll
        for (int ni = 0; ni < 2; ++ni) {
          int sB = dwi * 64 + wn * 32 + ni * 16 + lr;
          bf[ni] = *(const int4v*)(Bs + sB * 64 + (((quad ^ (sB >> 1)) & 3) * 16));
        }
        if (high) {
          #pragma unroll
          for (int mi = 0; mi < 4; ++mi)
            #pragma unroll
            for (int ni = 0; ni < 2; ++ni)
              acch[mi][ni] = __builtin_amdgcn_mfma_i32_16x16x64_i8(
                  af[mi], bf[ni], acch[mi][ni], 0, 0, 0);
        } else {
          #pragma unroll
          for (int mi = 0; mi < 4; ++mi)
            #pragma unroll
            for (int ni = 0; ni < 2; ++ni)
              accl[mi][ni] = __builtin_amdgcn_mfma_i32_16x16x64_i8(
                  af[mi], bf[ni], accl[mi][ni], 0, 0, 0);
        }
      }
    }
  }

  // ---- Epilogue: y = sc_h*acc_h + sc_l*acc_l + bias, direct dwordx4 stores
  #pragma unroll
  for (int mi = 0; mi < 4; ++mi) {
    int m = m0 + wm * 64 + mi * 16 + quad * 4;
    int b = m / HW, r = m - b * HW;
    float* obase = out + (size_t)b * (CH * HW) + r;
    #pragma unroll
    for (int ni = 0; ni < 2; ++ni) {
      int oc = oc0 + wn * 32 + ni * 16 + lr;
      float sch = scb[oc], scl = scb[128 + oc], bs = scb[256 + oc];
      float4v f;
      #pragma unroll
      for (int rg = 0; rg < 4; ++rg)
        f[rg] = sch * (float)acch[mi][ni][rg] + scl * (float)accl[mi][ni][rg] + bs;
      *(float4v*)(obase + (size_t)oc * HW) = f;
    }
  }
}

extern "C" void kernel_launch(void* const* d_in, const int* in_sizes, int n_in,
                              void* d_out, int out_size, void* d_ws, size_t ws_size,
                              hipStream_t stream) {
  const float* x  = (const float*)d_in[0];
  const float* wh = (const float*)d_in[1];
  const float* wl = (const float*)d_in[2];
  const float* sh = (const float*)d_in[3];
  const float* sl = (const float*)d_in[4];
  float* out = (float*)d_out;

  char* ws = (char*)d_ws;
  char* wqb  = ws + WQB_OFF;
  float* scb = (float*)(ws + SCB_OFF);
  int* zp    = (int*)(ws + ZP_OFF);
  char* aqn  = ws + AQN_OFF;

  quant_w_kernel<<<dim3(256), dim3(256), 0, stream>>>(wh, wl, sh, sl, wqb, scb, zp);
  maskquant_kernel<<<dim3(BATCH * 7 * 8), dim3(256), 0, stream>>>(x, sh, sl, aqn);
  conv_mfma_kernel<<<dim3(M_TOTAL / 128, 2), dim3(256), 0, stream>>>(
      wqb, aqn, (const char*)zp, scb, out);
}